// Round 1
// baseline (880.169 us; speedup 1.0000x reference)
//
#include <hip/hip_runtime.h>
#include <hip/hip_bf16.h>
#include <math.h>

#define Bn 32
#define CL 1024
#define QL 128
#define Hh 512
#define NEGV (-1e30f)

// ---------------- K0: out[r] = dot(X[r,:], w) + bias ----------------
__global__ __launch_bounds__(256) void rowdot_kernel(
    const float* __restrict__ X, const float* __restrict__ w,
    const float* __restrict__ bias, float* __restrict__ out, int nrows) {
  int row = blockIdx.x * 4 + (threadIdx.x >> 6);
  int lane = threadIdx.x & 63;
  if (row >= nrows) return;
  const float* x = X + (size_t)row * Hh;
  float s = 0.f;
  for (int h = lane; h < Hh; h += 64) s += x[h] * w[h];
  for (int off = 32; off > 0; off >>= 1) s += __shfl_down(s, off, 64);
  if (lane == 0) out[row] = s + (bias ? bias[0] : 0.f);
}

// ---------------- K1: S = (C*w3)@Q^T + rc + cq, + row softmax stats ----------------
__global__ __launch_bounds__(256) void s_kernel(
    const float* __restrict__ C, const float* __restrict__ Q,
    const float* __restrict__ w3, const int* __restrict__ Qmask,
    const float* __restrict__ rc, const float* __restrict__ cq,
    float* __restrict__ S, float* __restrict__ rowm, float* __restrict__ rowl) {
  __shared__ float sA[32][65];
  __shared__ float sB[32][129];
  __shared__ float sW[Hh];
  __shared__ int qm[QL];
  int b = blockIdx.y;
  int i0 = blockIdx.x * 64;
  int tid = threadIdx.x;
  if (tid < QL) qm[tid] = Qmask[b * QL + tid];
  for (int l = tid; l < Hh; l += 256) sW[l] = w3[l];
  __syncthreads();

  int tx = tid & 15, ty = tid >> 4;
  float acc[4][8] = {};
  const float* Cb = C + ((size_t)b * CL + i0) * Hh;
  const float* Qb = Q + (size_t)b * QL * Hh;

  for (int k0 = 0; k0 < Hh; k0 += 32) {
    for (int l = 0; l < 8; ++l) {           // A tile 64x32
      int idx = tid + l * 256;
      int kk = idx & 31, m = idx >> 5;
      sA[kk][m] = Cb[(size_t)m * Hh + k0 + kk] * sW[k0 + kk];
    }
    for (int l = 0; l < 16; ++l) {          // B tile 128x32
      int idx = tid + l * 256;
      int kk = idx & 31, j = idx >> 5;
      sB[kk][j] = Qb[(size_t)j * Hh + k0 + kk];
    }
    __syncthreads();
    for (int kk = 0; kk < 32; ++kk) {
      float a[4], bb[8];
      for (int r = 0; r < 4; ++r) a[r] = sA[kk][ty * 4 + r];
      for (int c = 0; c < 8; ++c) bb[c] = sB[kk][tx * 8 + c];
      for (int r = 0; r < 4; ++r)
        for (int c = 0; c < 8; ++c) acc[r][c] += a[r] * bb[c];
    }
    __syncthreads();
  }

  float* Srow = S + ((size_t)b * CL + i0) * QL;
  for (int r = 0; r < 4; ++r) {
    int i = ty * 4 + r;
    float rcv = rc[(size_t)b * CL + i0 + i];
    float vals[8];
    float vmax = -INFINITY;
    for (int c = 0; c < 8; ++c) {
      int j = tx * 8 + c;
      float s = acc[r][c] + rcv + cq[b * QL + j];
      vals[c] = s;
      Srow[(size_t)i * QL + j] = s;
      float v = qm[j] ? s : NEGV;
      vmax = fmaxf(vmax, v);
    }
    for (int off = 1; off < 16; off <<= 1) vmax = fmaxf(vmax, __shfl_xor(vmax, off, 64));
    float lsum = 0.f;
    for (int c = 0; c < 8; ++c) {
      int j = tx * 8 + c;
      float v = qm[j] ? vals[c] : NEGV;
      lsum += expf(v - vmax);
    }
    for (int off = 1; off < 16; off <<= 1) lsum += __shfl_xor(lsum, off, 64);
    if (tx == 0) {
      rowm[(size_t)b * CL + i0 + i] = vmax;
      rowl[(size_t)b * CL + i0 + i] = lsum;
    }
  }
}

// ---------------- K2: column softmax stats (online) ----------------
__global__ __launch_bounds__(512) void colstat_kernel(
    const float* __restrict__ S, const int* __restrict__ Cmask,
    float* __restrict__ colm, float* __restrict__ coll) {
  __shared__ int cm[CL];
  __shared__ float sm[4][QL], sl[4][QL];
  int b = blockIdx.x;
  int tid = threadIdx.x;
  for (int l = tid; l < CL; l += 512) cm[l] = Cmask[b * CL + l];
  __syncthreads();
  int j = tid & 127, ir = tid >> 7;
  float m = -INFINITY, l = 0.f;
  const float* Sb = S + (size_t)b * CL * QL;
  for (int i = ir; i < CL; i += 4) {
    float s = Sb[(size_t)i * QL + j];
    float v = cm[i] ? s : NEGV;
    float nm = fmaxf(m, v);
    l = l * expf(m - nm) + expf(v - nm);
    m = nm;
  }
  sm[ir][j] = m; sl[ir][j] = l;
  __syncthreads();
  if (tid < QL) {
    float M = sm[0][j], L = sl[0][j];
    for (int r = 1; r < 4; ++r) {
      float m2 = sm[r][j], l2 = sl[r][j];
      float nm = fmaxf(M, m2);
      L = L * expf(M - nm) + l2 * expf(m2 - nm);
      M = nm;
    }
    colm[b * QL + j] = M;
    coll[b * QL + j] = L;
  }
}

// ---------------- K3: T[j,h] = sum_i S_col[i,j] * C[i,h] ----------------
__global__ __launch_bounds__(256) void t_kernel(
    const float* __restrict__ S, const float* __restrict__ C,
    const int* __restrict__ Cmask, const float* __restrict__ colm,
    const float* __restrict__ coll, float* __restrict__ T) {
  __shared__ float sP[32][65];
  __shared__ float sC[32][65];
  __shared__ int cm[CL];
  __shared__ float cmj[64], clj[64];
  int b = blockIdx.z;
  int j0 = blockIdx.y * 64;
  int h0 = blockIdx.x * 64;
  int tid = threadIdx.x;
  for (int l = tid; l < CL; l += 256) cm[l] = Cmask[b * CL + l];
  if (tid < 64) {
    cmj[tid] = colm[b * QL + j0 + tid];
    clj[tid] = 1.f / coll[b * QL + j0 + tid];
  }
  __syncthreads();
  int tx = tid & 15, ty = tid >> 4;
  float acc[4][4] = {};
  const float* Sb = S + (size_t)b * CL * QL;
  const float* Cb = C + (size_t)b * CL * Hh;
  for (int i0 = 0; i0 < CL; i0 += 32) {
    for (int l = 0; l < 8; ++l) {
      int idx = tid + l * 256;
      int jj = idx & 63, kk = idx >> 6;
      float s = Sb[(size_t)(i0 + kk) * QL + j0 + jj];
      float v = cm[i0 + kk] ? s : NEGV;
      sP[kk][jj] = expf(v - cmj[jj]) * clj[jj];
      sC[kk][jj] = Cb[(size_t)(i0 + kk) * Hh + h0 + jj];
    }
    __syncthreads();
    for (int kk = 0; kk < 32; ++kk) {
      float a[4], bb[4];
      for (int r = 0; r < 4; ++r) a[r] = sP[kk][ty * 4 + r];
      for (int c = 0; c < 4; ++c) bb[c] = sC[kk][tx * 4 + c];
      for (int r = 0; r < 4; ++r)
        for (int c = 0; c < 4; ++c) acc[r][c] += a[r] * bb[c];
    }
    __syncthreads();
  }
  float* Tb = T + ((size_t)b * QL + j0) * Hh + h0;
  for (int r = 0; r < 4; ++r)
    for (int c = 0; c < 4; ++c)
      Tb[(size_t)(ty * 4 + r) * Hh + tx * 4 + c] = acc[r][c];
}

// ---------------- K4: A = P@Q, Bm = P@T, write [C, A, C*A, C*Bm] ----------------
__global__ __launch_bounds__(256) void out_kernel(
    const float* __restrict__ S, const float* __restrict__ C,
    const float* __restrict__ Q, const float* __restrict__ T,
    const int* __restrict__ Qmask, const float* __restrict__ rowm,
    const float* __restrict__ rowl, float* __restrict__ out) {
  __shared__ float sP[32][65];
  __shared__ float sQ[32][65];
  __shared__ float sT[32][65];
  __shared__ int qm[QL];
  __shared__ float rm[64], rl[64];
  int b = blockIdx.z;
  int i0 = blockIdx.y * 64;
  int h0 = blockIdx.x * 64;
  int tid = threadIdx.x;
  if (tid < QL) qm[tid] = Qmask[b * QL + tid];
  if (tid >= 128 && tid < 192) {
    int i = tid - 128;
    rm[i] = rowm[(size_t)b * CL + i0 + i];
    rl[i] = 1.f / rowl[(size_t)b * CL + i0 + i];
  }
  __syncthreads();
  int tx = tid & 15, ty = tid >> 4;
  float accA[4][4] = {}, accB[4][4] = {};
  const float* Sb = S + ((size_t)b * CL + i0) * QL;
  const float* Qb = Q + (size_t)b * QL * Hh + h0;
  const float* Tb = T + (size_t)b * QL * Hh + h0;
  for (int k0 = 0; k0 < QL; k0 += 32) {
    for (int l = 0; l < 8; ++l) {          // P tile 64 rows x 32 k
      int idx = tid + l * 256;
      int kk = idx & 31, mm = idx >> 5;
      float s = Sb[(size_t)mm * QL + k0 + kk];
      float v = qm[k0 + kk] ? s : NEGV;
      sP[kk][mm] = expf(v - rm[mm]) * rl[mm];
    }
    for (int l = 0; l < 8; ++l) {          // Q,T tiles 32 x 64
      int idx = tid + l * 256;
      int hh = idx & 63, kk = idx >> 6;
      sQ[kk][hh] = Qb[(size_t)(k0 + kk) * Hh + hh];
      sT[kk][hh] = Tb[(size_t)(k0 + kk) * Hh + hh];
    }
    __syncthreads();
    for (int kk = 0; kk < 32; ++kk) {
      float a[4], q4[4], t4[4];
      for (int r = 0; r < 4; ++r) a[r] = sP[kk][ty * 4 + r];
      for (int c = 0; c < 4; ++c) { q4[c] = sQ[kk][tx * 4 + c]; t4[c] = sT[kk][tx * 4 + c]; }
      for (int r = 0; r < 4; ++r)
        for (int c = 0; c < 4; ++c) { accA[r][c] += a[r] * q4[c]; accB[r][c] += a[r] * t4[c]; }
    }
    __syncthreads();
  }
  for (int r = 0; r < 4; ++r) {
    int i = i0 + ty * 4 + r;
    const float* Crow = C + ((size_t)b * CL + i) * Hh + h0;
    float* orow = out + ((size_t)b * CL + i) * (size_t)(4 * Hh);
    for (int c = 0; c < 4; ++c) {
      int h = tx * 4 + c;
      float cv = Crow[h];
      float av = accA[r][c], bv = accB[r][c];
      orow[h0 + h] = cv;
      orow[Hh + h0 + h] = av;
      orow[2 * Hh + h0 + h] = cv * av;
      orow[3 * Hh + h0 + h] = cv * bv;
    }
  }
}

extern "C" void kernel_launch(void* const* d_in, const int* in_sizes, int n_in,
                              void* d_out, int out_size, void* d_ws, size_t ws_size,
                              hipStream_t stream) {
  const float* C = (const float*)d_in[0];
  const float* Q = (const float*)d_in[1];
  const int* Cmask = (const int*)d_in[2];
  const int* Qmask = (const int*)d_in[3];
  const float* w = (const float*)d_in[4];
  const float* bptr = (const float*)d_in[5];
  float* out = (float*)d_out;
  float* ws = (float*)d_ws;

  // workspace layout (floats)
  float* rc   = ws;                 // 32768
  float* cq   = ws + 32768;         // 4096
  float* rowm = ws + 36864;         // 32768
  float* rowl = ws + 69632;         // 32768
  float* colm = ws + 102400;        // 4096
  float* coll = ws + 106496;        // 4096
  float* S    = ws + 110592;        // 4194304
  float* T    = ws + 4304896;       // 2097152  (total ~25.6 MB)

  rowdot_kernel<<<dim3((Bn * CL) / 4), 256, 0, stream>>>(C, w, nullptr, rc, Bn * CL);
  rowdot_kernel<<<dim3((Bn * QL) / 4), 256, 0, stream>>>(Q, w + Hh, bptr, cq, Bn * QL);
  s_kernel<<<dim3(CL / 64, Bn), 256, 0, stream>>>(C, Q, w + 2 * Hh, Qmask, rc, cq, S, rowm, rowl);
  colstat_kernel<<<dim3(Bn), 512, 0, stream>>>(S, Cmask, colm, coll);
  t_kernel<<<dim3(Hh / 64, QL / 64, Bn), 256, 0, stream>>>(S, C, Cmask, colm, coll, T);
  out_kernel<<<dim3(Hh / 64, CL / 64, Bn), 256, 0, stream>>>(S, C, Q, T, Qmask, rowm, rowl, out);
}

// Round 2
// 481.290 us; speedup vs baseline: 1.8288x; 1.8288x over previous
//
#include <hip/hip_runtime.h>
#include <hip/hip_bf16.h>
#include <math.h>

#define Bn 32
#define CL 1024
#define QL 128
#define Hh 512
#define NEGV (-1e30f)

typedef short bf16x8 __attribute__((ext_vector_type(8)));
typedef float f32x4 __attribute__((ext_vector_type(4)));

__device__ inline unsigned short f2bf(float x) {
  union { float f; unsigned u; } v; v.f = x;
  unsigned r = v.u + 0x7fff + ((v.u >> 16) & 1);
  return (unsigned short)(r >> 16);
}
__device__ inline unsigned packbf(float x, float y) {
  return (unsigned)f2bf(x) | ((unsigned)f2bf(y) << 16);
}

// ---------------- rowdot: out[r] = dot(X[r,:], w) + bias ----------------
__global__ __launch_bounds__(256) void rowdot_kernel(
    const float* __restrict__ X, const float* __restrict__ w,
    const float* __restrict__ bias, float* __restrict__ out, int nrows) {
  int row = blockIdx.x * 4 + (threadIdx.x >> 6);
  int lane = threadIdx.x & 63;
  if (row >= nrows) return;
  const float* x = X + (size_t)row * Hh;
  float s = 0.f;
  for (int h = lane; h < Hh; h += 64) s += x[h] * w[h];
  for (int off = 32; off > 0; off >>= 1) s += __shfl_down(s, off, 64);
  if (lane == 0) out[row] = s + (bias ? bias[0] : 0.f);
}

// ---------------- S = (C*w3)@Q^T + rc + cq; row softmax -> S fp32 + P_row bf16 ----
__global__ __launch_bounds__(256) void s_mfma_kernel(
    const float* __restrict__ C, const float* __restrict__ Q,
    const float* __restrict__ w3, const int* __restrict__ Qmask,
    const float* __restrict__ rc, const float* __restrict__ cq,
    float* __restrict__ S, unsigned short* __restrict__ Prow) {
  __shared__ unsigned sA[64 * 16];   // 64 rows x 32 bf16 (C*w3)
  __shared__ unsigned sB[128 * 16];  // 128 rows x 32 bf16 (Q)
  __shared__ float sW[Hh];
  __shared__ int qm[QL];
  int b = blockIdx.y, i0 = blockIdx.x * 64, t = threadIdx.x;
  if (t < QL) qm[t] = Qmask[b * QL + t];
  for (int l = t; l < Hh; l += 256) sW[l] = w3[l];
  __syncthreads();
  int lane = t & 63, w = t >> 6;
  int lanen = lane & 15, quad = lane >> 4;
  f32x4 acc[8];
  for (int nt = 0; nt < 8; ++nt) acc[nt] = (f32x4){0.f, 0.f, 0.f, 0.f};
  const float* Cb = C + ((size_t)b * CL + i0) * Hh;
  const float* Qb = Q + (size_t)b * QL * Hh;
  for (int k0 = 0; k0 < Hh; k0 += 32) {
    for (int l = 0; l < 4; ++l) {                 // A: 64x32
      int idx = t + l * 256; int c = idx & 15, rr = idx >> 4;
      float2 v = *(const float2*)(Cb + (size_t)rr * Hh + k0 + c * 2);
      sA[rr * 16 + c] = packbf(v.x * sW[k0 + c * 2], v.y * sW[k0 + c * 2 + 1]);
    }
    for (int l = 0; l < 8; ++l) {                 // B: 128x32
      int idx = t + l * 256; int c = idx & 15, j = idx >> 4;
      float2 v = *(const float2*)(Qb + (size_t)j * Hh + k0 + c * 2);
      sB[j * 16 + c] = packbf(v.x, v.y);
    }
    __syncthreads();
    bf16x8 a = *(const bf16x8*)(sA + (w * 16 + lanen) * 16 + quad * 4);
    for (int nt = 0; nt < 8; ++nt) {
      bf16x8 bb = *(const bf16x8*)(sB + (nt * 16 + lanen) * 16 + quad * 4);
      acc[nt] = __builtin_amdgcn_mfma_f32_16x16x32_bf16(a, bb, acc[nt], 0, 0, 0);
    }
    __syncthreads();
  }
  float cqv[8]; int qmv[8];
  for (int nt = 0; nt < 8; ++nt) {
    int j = nt * 16 + lanen;
    cqv[nt] = cq[b * QL + j]; qmv[nt] = qm[j];
  }
  int rowbase = i0 + w * 16 + quad * 4;
  for (int r = 0; r < 4; ++r) {
    int row = rowbase + r;
    float rcv = rc[b * CL + row];
    float vals[8], mv = -INFINITY;
    for (int nt = 0; nt < 8; ++nt) {
      float val = acc[nt][r] + rcv + cqv[nt];
      vals[nt] = val;
      mv = fmaxf(mv, qmv[nt] ? val : NEGV);
    }
    for (int off = 1; off < 16; off <<= 1) mv = fmaxf(mv, __shfl_xor(mv, off, 64));
    float ls = 0.f;
    for (int nt = 0; nt < 8; ++nt) ls += __expf((qmv[nt] ? vals[nt] : NEGV) - mv);
    for (int off = 1; off < 16; off <<= 1) ls += __shfl_xor(ls, off, 64);
    float linv = 1.f / ls;
    size_t base = ((size_t)b * CL + row) * QL;
    for (int nt = 0; nt < 8; ++nt) {
      int j = nt * 16 + lanen;
      S[base + j] = vals[nt];
      Prow[base + j] = f2bf(__expf((qmv[nt] ? vals[nt] : NEGV) - mv) * linv);
    }
  }
}

// ---------------- column softmax stats, 2-stage ----------------
__global__ __launch_bounds__(256) void colstat1_kernel(
    const float* __restrict__ S, const int* __restrict__ Cmask,
    float* __restrict__ partm, float* __restrict__ partl) {
  __shared__ int cm[64];
  __shared__ float sm[QL], sl[QL];
  int b = blockIdx.y, chunk = blockIdx.x, t = threadIdx.x;
  int i0 = chunk * 64;
  if (t < 64) cm[t] = Cmask[b * CL + i0 + t];
  __syncthreads();
  int j = t & 127, ir = t >> 7;
  float m = -INFINITY, l = 0.f;
  const float* Sb = S + ((size_t)b * CL + i0) * QL;
  for (int i = ir; i < 64; i += 2) {
    float v = cm[i] ? Sb[(size_t)i * QL + j] : NEGV;
    float nm = fmaxf(m, v);
    l = l * __expf(m - nm) + __expf(v - nm);
    m = nm;
  }
  if (ir == 1) { sm[j] = m; sl[j] = l; }
  __syncthreads();
  if (ir == 0) {
    float m2 = sm[j], l2 = sl[j];
    float nm = fmaxf(m, m2);
    float L = l * __expf(m - nm) + l2 * __expf(m2 - nm);
    partm[(b * 16 + chunk) * QL + j] = nm;
    partl[(b * 16 + chunk) * QL + j] = L;
  }
}

__global__ __launch_bounds__(128) void colstat2_kernel(
    const float* __restrict__ partm, const float* __restrict__ partl,
    float* __restrict__ colm, float* __restrict__ colinv) {
  int b = blockIdx.x, j = threadIdx.x;
  float m = -INFINITY, L = 0.f;
  for (int c = 0; c < 16; ++c) {
    float m2 = partm[(b * 16 + c) * QL + j], l2 = partl[(b * 16 + c) * QL + j];
    float nm = fmaxf(m, m2);
    L = L * __expf(m - nm) + l2 * __expf(m2 - nm);
    m = nm;
  }
  colm[b * QL + j] = m;
  colinv[b * QL + j] = 1.f / L;
}

// ---------------- P_col^T bf16 [b][j][i] ----------------
__global__ __launch_bounds__(256) void pcol_kernel(
    const float* __restrict__ S, const int* __restrict__ Cmask,
    const float* __restrict__ colm, const float* __restrict__ colinv,
    unsigned short* __restrict__ PT) {
  __shared__ float tile[64 * 129];
  __shared__ int cm[64];
  __shared__ float cmj[QL], civ[QL];
  int b = blockIdx.y, i0 = blockIdx.x * 64, t = threadIdx.x;
  if (t < 64) cm[t] = Cmask[b * CL + i0 + t];
  if (t >= 128) { int j = t - 128; cmj[j] = colm[b * QL + j]; civ[j] = colinv[b * QL + j]; }
  __syncthreads();
  const float* Sb = S + ((size_t)b * CL + i0) * QL;
  for (int l = 0; l < 32; ++l) {
    int idx = t + l * 256; int j = idx & 127, il = idx >> 7;
    float v = cm[il] ? Sb[(size_t)il * QL + j] : NEGV;
    tile[il * 129 + j] = __expf(v - cmj[j]) * civ[j];
  }
  __syncthreads();
  unsigned* PTu = (unsigned*)PT;
  for (int l = 0; l < 16; ++l) {
    int idx = t + l * 256; int c = idx & 31, j = idx >> 5;
    PTu[(((size_t)b * QL + j) * CL + i0) / 2 + c] =
        packbf(tile[(2 * c) * 129 + j], tile[(2 * c + 1) * 129 + j]);
  }
}

// ---------------- TT[h][j] = sum_i C^T[h,i] * Pcol[i,j]  (bf16 out) ----------------
__global__ __launch_bounds__(256) void t_mfma_kernel(
    const float* __restrict__ C, const unsigned short* __restrict__ PT,
    unsigned short* __restrict__ TT) {
  __shared__ float ftile[32 * 33];
  __shared__ unsigned sA[32 * 16];   // 32 h x 32 i bf16
  __shared__ unsigned sB[128 * 16];  // 128 j x 32 i bf16
  int b = blockIdx.y, h0 = blockIdx.x * 32, t = threadIdx.x;
  int lane = t & 63, w = t >> 6;
  int lanen = lane & 15, quad = lane >> 4;
  int mw = w >> 1, nw = w & 1;
  f32x4 acc[4];
  for (int nt = 0; nt < 4; ++nt) acc[nt] = (f32x4){0.f, 0.f, 0.f, 0.f};
  const float* Cb = C + (size_t)b * CL * Hh;
  const unsigned* PTu = (const unsigned*)PT + ((size_t)b * QL * CL) / 2;
  for (int i0 = 0; i0 < CL; i0 += 32) {
    for (int l = 0; l < 4; ++l) {                 // fp32 C tile, coalesced
      int idx = t + l * 256; int hh = idx & 31, ii = idx >> 5;
      ftile[ii * 33 + hh] = Cb[(size_t)(i0 + ii) * Hh + h0 + hh];
    }
    for (int l = 0; l < 8; ++l) {                 // B: PT direct copy
      int idx = t + l * 256; int c = idx & 15, j = idx >> 4;
      sB[j * 16 + c] = PTu[(size_t)j * (CL / 2) + i0 / 2 + c];
    }
    __syncthreads();
    for (int l = 0; l < 2; ++l) {                 // transpose-pack A
      int idx = t + l * 256; int c = idx & 15, hh = idx >> 4;
      sA[hh * 16 + c] = packbf(ftile[(2 * c) * 33 + hh], ftile[(2 * c + 1) * 33 + hh]);
    }
    __syncthreads();
    bf16x8 a = *(const bf16x8*)(sA + (mw * 16 + lanen) * 16 + quad * 4);
    for (int nt = 0; nt < 4; ++nt) {
      bf16x8 bb = *(const bf16x8*)(sB + (nw * 64 + nt * 16 + lanen) * 16 + quad * 4);
      acc[nt] = __builtin_amdgcn_mfma_f32_16x16x32_bf16(a, bb, acc[nt], 0, 0, 0);
    }
    __syncthreads();
  }
  for (int nt = 0; nt < 4; ++nt)
    for (int r = 0; r < 4; ++r) {
      int h = h0 + mw * 16 + quad * 4 + r;
      int j = nw * 64 + nt * 16 + lanen;
      TT[((size_t)b * Hh + h) * QL + j] = f2bf(acc[nt][r]);
    }
}

// ---------------- out: A = P@Q, Bm = P@T; write [C, A, C*A, C*Bm] ----------------
__global__ __launch_bounds__(256) void out_mfma_kernel(
    const unsigned short* __restrict__ Prow, const unsigned short* __restrict__ TT,
    const float* __restrict__ Q, const float* __restrict__ C,
    float* __restrict__ out) {
  __shared__ float ftile[32 * 65];
  __shared__ unsigned sP[64 * 16];
  __shared__ unsigned sQT[64 * 16];
  __shared__ unsigned sTT[64 * 16];
  int b = blockIdx.z, i0 = blockIdx.y * 64, h0 = blockIdx.x * 64, t = threadIdx.x;
  int lane = t & 63, w = t >> 6;
  int lanen = lane & 15, quad = lane >> 4;
  f32x4 accA[4], accB[4];
  for (int nt = 0; nt < 4; ++nt) {
    accA[nt] = (f32x4){0.f, 0.f, 0.f, 0.f};
    accB[nt] = (f32x4){0.f, 0.f, 0.f, 0.f};
  }
  const unsigned* Pu = (const unsigned*)Prow + ((size_t)b * CL + i0) * (QL / 2);
  const unsigned* Tu = (const unsigned*)TT + ((size_t)b * Hh + h0) * (QL / 2);
  const float* Qb = Q + (size_t)b * QL * Hh;
  for (int k0 = 0; k0 < QL; k0 += 32) {
    for (int l = 0; l < 4; ++l) {
      int idx = t + l * 256; int c = idx & 15, rr = idx >> 4;
      sP[rr * 16 + c] = Pu[(size_t)rr * (QL / 2) + k0 / 2 + c];
      sTT[rr * 16 + c] = Tu[(size_t)rr * (QL / 2) + k0 / 2 + c];
    }
    for (int l = 0; l < 8; ++l) {                 // fp32 Q tile
      int idx = t + l * 256; int hh = idx & 63, jj = idx >> 6;
      ftile[jj * 65 + hh] = Qb[(size_t)(k0 + jj) * Hh + h0 + hh];
    }
    __syncthreads();
    for (int l = 0; l < 4; ++l) {                 // transpose-pack Q^T
      int idx = t + l * 256; int c = idx & 15, hh = idx >> 4;
      sQT[hh * 16 + c] = packbf(ftile[(2 * c) * 65 + hh], ftile[(2 * c + 1) * 65 + hh]);
    }
    __syncthreads();
    bf16x8 a = *(const bf16x8*)(sP + (w * 16 + lanen) * 16 + quad * 4);
    for (int nt = 0; nt < 4; ++nt) {
      bf16x8 bq = *(const bf16x8*)(sQT + (nt * 16 + lanen) * 16 + quad * 4);
      bf16x8 bt = *(const bf16x8*)(sTT + (nt * 16 + lanen) * 16 + quad * 4);
      accA[nt] = __builtin_amdgcn_mfma_f32_16x16x32_bf16(a, bq, accA[nt], 0, 0, 0);
      accB[nt] = __builtin_amdgcn_mfma_f32_16x16x32_bf16(a, bt, accB[nt], 0, 0, 0);
    }
    __syncthreads();
  }
  for (int r = 0; r < 4; ++r) {
    int i = i0 + w * 16 + quad * 4 + r;
    const float* Crow = C + ((size_t)b * CL + i) * Hh;
    float* orow = out + ((size_t)b * CL + i) * (size_t)(4 * Hh);
    for (int nt = 0; nt < 4; ++nt) {
      int h = h0 + nt * 16 + lanen;
      float cv = Crow[h];
      float av = accA[nt][r], bv = accB[nt][r];
      orow[h] = cv;
      orow[Hh + h] = av;
      orow[2 * Hh + h] = cv * av;
      orow[3 * Hh + h] = cv * bv;
    }
  }
}

extern "C" void kernel_launch(void* const* d_in, const int* in_sizes, int n_in,
                              void* d_out, int out_size, void* d_ws, size_t ws_size,
                              hipStream_t stream) {
  const float* C = (const float*)d_in[0];
  const float* Q = (const float*)d_in[1];
  const int* Cmask = (const int*)d_in[2];
  const int* Qmask = (const int*)d_in[3];
  const float* w = (const float*)d_in[4];
  const float* bptr = (const float*)d_in[5];
  float* out = (float*)d_out;
  float* f = (float*)d_ws;

  // workspace layout
  float* rc     = f;                  // 32768
  float* cq     = f + 32768;          // 4096
  float* colm   = f + 36864;          // 4096
  float* colinv = f + 40960;          // 4096
  float* partm  = f + 45056;          // 65536
  float* partl  = f + 110592;         // 65536
  float* S      = f + 176128;         // 4194304 (16 MB)
  unsigned short* Prow = (unsigned short*)(f + 4370432);  // 8 MB
  unsigned short* PT   = Prow + 4194304;                  // 8 MB
  unsigned short* TT   = PT + 4194304;                    // 4 MB  (total ~38.5 MB)

  rowdot_kernel<<<dim3((Bn * CL) / 4), 256, 0, stream>>>(C, w, nullptr, rc, Bn * CL);
  rowdot_kernel<<<dim3((Bn * QL) / 4), 256, 0, stream>>>(Q, w + Hh, bptr, cq, Bn * QL);
  s_mfma_kernel<<<dim3(CL / 64, Bn), 256, 0, stream>>>(C, Q, w + 2 * Hh, Qmask, rc, cq, S, Prow);
  colstat1_kernel<<<dim3(16, Bn), 256, 0, stream>>>(S, Cmask, partm, partl);
  colstat2_kernel<<<dim3(Bn), 128, 0, stream>>>(partm, partl, colm, colinv);
  pcol_kernel<<<dim3(CL / 64, Bn), 256, 0, stream>>>(S, Cmask, colm, colinv, PT);
  t_mfma_kernel<<<dim3(Hh / 32, Bn), 256, 0, stream>>>(C, PT, TT);
  out_mfma_kernel<<<dim3(Hh / 64, CL / 64, Bn), 256, 0, stream>>>(Prow, TT, Q, C, out);
}